// Round 7
// baseline (1759.987 us; speedup 1.0000x reference)
//
#include <hip/hip_runtime.h>
#include <math.h>

#define B_ 256
#define D_ 564
#define S_ 40
#define NB_ 6
#define N_ 2256          // 4*D
#define M_ 10240         // B*S
#define DD_ 318096       // D*D
#define KP_ 576          // D padded to multiple of 32 for MFMA K
#define OUTIN_ 1128
#define HW_ 288          // u32 words per h row (576 f16)
#define BSTRIDE_ 32      // u32 stride between per-bg barrier counters (128 B)

typedef _Float16 f16;
typedef _Float16 f16x4 __attribute__((ext_vector_type(4)));
typedef _Float16 f16x8 __attribute__((ext_vector_type(8)));
typedef float    f32x4 __attribute__((ext_vector_type(4)));

// ---------------------------------------------------------------------------
// P) prep: W,R (l,g,k,e) fp32 -> (l,g,e,k) fp16, k padded 564->576 with zeros
// ---------------------------------------------------------------------------
__global__ __launch_bounds__(256) void k_prep(const float* __restrict__ Wg,
                                              const float* __restrict__ Rg,
                                              f16* __restrict__ Wt,
                                              f16* __restrict__ Rt) {
    __shared__ float tile[32][33];
    int bz  = blockIdx.z;            // 0..47
    int sel = bz / 24;               // 0 = W, 1 = R
    int lg  = bz - sel * 24;         // layer*4 + gate
    const float* src = (sel ? Rg : Wg) + (size_t)lg * DD_;
    f16*         dst = (sel ? Rt : Wt) + (size_t)lg * (D_ * KP_);
    int k0 = blockIdx.x * 32, e0 = blockIdx.y * 32;
    int j = threadIdx.x & 31;
    for (int i = threadIdx.x >> 5; i < 32; i += 8) {
        int k = k0 + i, e = e0 + j;
        tile[i][j] = (k < D_ && e < D_) ? src[(size_t)k * D_ + e] : 0.f;
    }
    __syncthreads();
    for (int i = threadIdx.x >> 5; i < 32; i += 8) {
        int e = e0 + i, k = k0 + j;
        if (e < D_ && k < KP_) dst[(size_t)e * KP_ + k] = (f16)tile[j][i];
    }
}

// ---------------------------------------------------------------------------
// 0) transpose inp (B, D, S) -> x (B, S, D)
// ---------------------------------------------------------------------------
__global__ __launch_bounds__(256) void k_transpose(const float* __restrict__ inp,
                                                   float* __restrict__ x) {
    __shared__ float tile[64][41];
    int b  = blockIdx.y;
    int d0 = blockIdx.x * 64;
    const float* ip = inp + (size_t)b * (D_ * S_);
    for (int idx = threadIdx.x; idx < 64 * 40; idx += 256) {
        int i = idx / 40, s = idx - i * 40;
        if (d0 + i < D_) tile[i][s] = ip[(size_t)(d0 + i) * S_ + s];
    }
    __syncthreads();
    float* xp = x + (size_t)b * (D_ * S_);
    for (int idx = threadIdx.x; idx < 40 * 64; idx += 256) {
        int j = idx & 63, s = idx >> 6;
        if (d0 + j < D_) xp[(size_t)s * D_ + d0 + j] = tile[j][s];
    }
}

// ---------------------------------------------------------------------------
// 1) fused: x += h (prev layer, optional) + LayerNorm row stats
//    h layout (S, B, KP) f16
// ---------------------------------------------------------------------------
__global__ __launch_bounds__(256) void k_addh_lnstats(float* __restrict__ x,
                                                      const f16* __restrict__ h,
                                                      int addh,
                                                      float* __restrict__ lmu,
                                                      float* __restrict__ lrs) {
    int row  = blockIdx.x * 4 + (threadIdx.x >> 6);
    int lane = threadIdx.x & 63;
    float* xp = x + (size_t)row * D_;
    int b = row / S_, s = row - b * S_;
    const f16* hp = h + ((size_t)s * B_ + b) * KP_;
    float s1 = 0.f, s2 = 0.f;
    if (addh) {
        for (int i = lane; i < D_; i += 64) {
            float v = xp[i] + (float)hp[i];
            xp[i] = v;
            s1 += v;
            s2 += v * v;
        }
    } else {
        for (int i = lane; i < D_; i += 64) {
            float v = xp[i];
            s1 += v;
            s2 += v * v;
        }
    }
    for (int off = 32; off; off >>= 1) {
        s1 += __shfl_down(s1, off);
        s2 += __shfl_down(s2, off);
    }
    if (lane == 0) {
        float mu  = s1 * (1.f / D_);
        float var = fmaxf(s2 * (1.f / D_) - mu * mu, 0.f);
        lmu[row] = mu;
        lrs[row] = rsqrtf(var + 1e-5f);
    }
}

// ---------------------------------------------------------------------------
// LN-fused A-chunk load: 8 fp32 from x row -> LN -> f16x8 (zero pad k>=564)
// ---------------------------------------------------------------------------
static __device__ __forceinline__ f16x8 ln_chunk(const float* __restrict__ xr,
                                                 const float* __restrict__ lg,
                                                 const float* __restrict__ lb,
                                                 float mu, float rs, int kk) {
    f16x8 o;
    if (kk + 8 <= D_) {
        float4 v0 = *(const float4*)(xr + kk);
        float4 v1 = *(const float4*)(xr + kk + 4);
        float4 g0 = *(const float4*)(lg + kk);
        float4 g1 = *(const float4*)(lg + kk + 4);
        float4 c0 = *(const float4*)(lb + kk);
        float4 c1 = *(const float4*)(lb + kk + 4);
        o[0] = (f16)((v0.x - mu) * rs * g0.x + c0.x);
        o[1] = (f16)((v0.y - mu) * rs * g0.y + c0.y);
        o[2] = (f16)((v0.z - mu) * rs * g0.z + c0.z);
        o[3] = (f16)((v0.w - mu) * rs * g0.w + c0.w);
        o[4] = (f16)((v1.x - mu) * rs * g1.x + c1.x);
        o[5] = (f16)((v1.y - mu) * rs * g1.y + c1.y);
        o[6] = (f16)((v1.z - mu) * rs * g1.z + c1.z);
        o[7] = (f16)((v1.w - mu) * rs * g1.w + c1.w);
    } else {
#pragma unroll
        for (int j = 0; j < 8; ++j) {
            int k = kk + j;
            float v = (k < D_) ? (xr[k] - mu) * rs * lg[k] + lb[k] : 0.f;
            o[j] = (f16)v;
        }
    }
    return o;
}

// ---------------------------------------------------------------------------
// 2) pre-GEMM (MFMA fp16), 128x128 tile, 4 waves, 4x4 frags/wave.
//    A = LN(x) computed inline (no hA buffer).  -> pre2 (s, b, e, gate) f16
// ---------------------------------------------------------------------------
__global__ __launch_bounds__(256) void k_pregemm(
        const float* __restrict__ x,
        const f16* __restrict__ Wt,     // (4,564,576)
        const float* __restrict__ bgl,
        const float* __restrict__ lg,
        const float* __restrict__ lb,
        const float* __restrict__ lmu,
        const float* __restrict__ lrs,
        f16* __restrict__ pre2) {
    __shared__ __align__(16) f16 As[128 * 40];
    __shared__ __align__(16) f16 Bs[128 * 40];
    const int tid  = threadIdx.x;
    const int wave = tid >> 6, lane = tid & 63;
    const int quad = lane >> 4, l16 = lane & 15;
    const int wm = wave & 1, wn = wave >> 1;
    const int m0 = blockIdx.x * 128, n0 = blockIdx.y * 128;

    // A-load role: row am, k-half ah
    const int am = tid & 127, ah = tid >> 7;
    const int m  = m0 + am;                 // m = b*40 + s (x row order)
    const float* xr = x + (size_t)m * D_;
    const float mu = lmu[m], rsg = lrs[m];

    // B-load role: col bn2, k-half bkc
    const int bn2 = tid & 127, bkc = tid >> 7;
    const int nj  = n0 + bn2;
    const bool nok = nj < N_;
    const int njc = nok ? nj : N_ - 1;
    const int gj  = njc / D_, ej = njc - gj * D_;
    const f16* wp = Wt + (size_t)(gj * D_ + ej) * KP_;

    f32x4 acc[4][4];
#pragma unroll
    for (int i = 0; i < 4; ++i)
#pragma unroll
        for (int j = 0; j < 4; ++j) acc[i][j] = (f32x4){0.f, 0.f, 0.f, 0.f};

    for (int k0 = 0; k0 < KP_; k0 += 32) {
        f16x8 a0 = ln_chunk(xr, lg, lb, mu, rsg, k0 + ah * 16);
        f16x8 a1 = ln_chunk(xr, lg, lb, mu, rsg, k0 + ah * 16 + 8);
        f16x8 b0 = (f16x8){}, b1 = (f16x8){};
        if (nok) {
            b0 = *(const f16x8*)(wp + k0 + bkc * 16);
            b1 = *(const f16x8*)(wp + k0 + bkc * 16 + 8);
        }
        __syncthreads();
        *(f16x8*)(As + am * 40 + ah * 16)      = a0;
        *(f16x8*)(As + am * 40 + ah * 16 + 8)  = a1;
        *(f16x8*)(Bs + bn2 * 40 + bkc * 16)     = b0;
        *(f16x8*)(Bs + bn2 * 40 + bkc * 16 + 8) = b1;
        __syncthreads();
        f16x8 bf[4];
#pragma unroll
        for (int fn = 0; fn < 4; ++fn)
            bf[fn] = *(const f16x8*)(Bs + (wn * 64 + fn * 16 + l16) * 40 + quad * 8);
#pragma unroll
        for (int fm = 0; fm < 4; ++fm) {
            f16x8 af = *(const f16x8*)(As + (wm * 64 + fm * 16 + l16) * 40 + quad * 8);
#pragma unroll
            for (int fn = 0; fn < 4; ++fn)
                acc[fm][fn] = __builtin_amdgcn_mfma_f32_16x16x32_f16(
                                  af, bf[fn], acc[fm][fn], 0, 0, 0);
        }
    }

#pragma unroll
    for (int fn = 0; fn < 4; ++fn) {
        int ncol = n0 + wn * 64 + fn * 16 + l16;
        if (ncol >= N_) continue;
        float bias = bgl[ncol];
        int g2 = ncol / D_, e2 = ncol - g2 * D_;
#pragma unroll
        for (int fm = 0; fm < 4; ++fm)
#pragma unroll
            for (int r = 0; r < 4; ++r) {
                int mm = m0 + wm * 64 + fm * 16 + quad * 4 + r;
                int bb = mm / S_, ss2 = mm - bb * S_;
                pre2[(((size_t)ss2 * B_ + bb) * D_ + e2) * 4 + g2] =
                    (f16)(acc[fm][fn][r] + bias);
            }
    }
}

// ---------------------------------------------------------------------------
// 3) persistent sLSTM recurrence (unchanged from round 6 — keep the win).
// ---------------------------------------------------------------------------
__global__ __launch_bounds__(576, 1) void k_rec_persist(
        const f16* __restrict__ Rt,      // (4,564,576) layer slice
        const f16* __restrict__ pre2,    // (40,256,564,4) f16
        unsigned* __restrict__ hbuf,     // (40, 256, 288) u32
        unsigned* __restrict__ bar,      // 16 counters, stride BSTRIDE_ u32
        int layer) {
    __shared__ __align__(16) f16 hs[16 * 584];   // h tile, padded rows
    __shared__ __align__(16) float gbuf[144 * 16];

    const int tid  = threadIdx.x;
    const int et   = blockIdx.x;
    const int bg   = blockIdx.y;
    const int wave = tid >> 6, lane = tid & 63;
    const int quad = lane >> 4, l16 = lane & 15;

    const int c  = wave * 16 + l16;
    const int g  = c / 36, el = c - g * 36;
    const int e  = et * 36 + el;
    const int ec = (e < D_) ? e : D_ - 1;

    f16x8 breg[18];
    {
        const f16* rp = Rt + (size_t)(g * D_ + ec) * KP_ + quad * 8;
#pragma unroll
        for (int kc = 0; kc < 18; ++kc)
            breg[kc] = *(const f16x8*)(rp + kc * 32);
    }

    const int b_loc = tid & 15, el2 = tid >> 4;
    const int e2  = et * 36 + el2;
    const int b   = bg * 16 + b_loc;
    const bool eok = (e2 < D_);
    const int ec2 = eok ? e2 : D_ - 1;

    float cv = 0.f, nv = 0.f, mv = 0.f;

    unsigned* barp = bar + bg * BSTRIDE_;
    const unsigned base = (unsigned)layer * 640u;

    f16x4 pf = *(const f16x4*)(pre2 + (size_t)b * D_ * 4 + ec2 * 4);

    for (int t = 0; t < S_; ++t) {
        if (t > 0) {
            if (tid == 0) {
                unsigned tgt = base + 16u * (unsigned)t;
                for (;;) {
                    unsigned v;
                    asm volatile(
                        "global_load_dword %0, %1, off sc0 sc1\n\t"
                        "s_waitcnt vmcnt(0)"
                        : "=v"(v) : "v"(barp) : "memory");
                    if (v >= tgt) break;
                    __builtin_amdgcn_s_sleep(1);
                }
            }
            __syncthreads();
            const unsigned long long* hsrc = (const unsigned long long*)
                (hbuf + (size_t)(t - 1) * (B_ * HW_) + (size_t)bg * 16 * HW_);
#pragma unroll
            for (int p = 0; p < 4; ++p) {
                int ch  = tid + p * 576;
                int row = ch / 144, col = ch - row * 144;
                unsigned long long v = __hip_atomic_load(
                    hsrc + (size_t)row * 144 + col,
                    __ATOMIC_RELAXED, __HIP_MEMORY_SCOPE_AGENT);
                *(unsigned long long*)(hs + row * 584 + col * 4) = v;
            }
            __syncthreads();
            f32x4 a0 = (f32x4){0.f, 0.f, 0.f, 0.f};
            f32x4 a1 = (f32x4){0.f, 0.f, 0.f, 0.f};
            const f16* hl = hs + l16 * 584 + quad * 8;
#pragma unroll
            for (int kc = 0; kc < 18; kc += 2) {
                f16x8 f0 = *(const f16x8*)(hl + kc * 32);
                f16x8 f1 = *(const f16x8*)(hl + kc * 32 + 32);
                a0 = __builtin_amdgcn_mfma_f32_16x16x32_f16(f0, breg[kc],     a0, 0, 0, 0);
                a1 = __builtin_amdgcn_mfma_f32_16x16x32_f16(f1, breg[kc + 1], a1, 0, 0, 0);
            }
            f32x4 acc = a0 + a1;
#pragma unroll
            for (int r = 0; r < 4; ++r)
                gbuf[c * 16 + quad * 4 + r] = acc[r];
            __syncthreads();
        }

        float hn = 0.f;
        if (eok) {
            float it = (float)pf[0];
            float ft = (float)pf[1];
            float zt = (float)pf[2];
            float ot = (float)pf[3];
            if (t > 0) {
                it += gbuf[(0 * 36 + el2) * 16 + b_loc];
                ft += gbuf[(1 * 36 + el2) * 16 + b_loc];
                zt += gbuf[(2 * 36 + el2) * 16 + b_loc];
                ot += gbuf[(3 * 36 + el2) * 16 + b_loc];
            }
            float mn = fmaxf(ft + mv, it);
            float iv = __expf(it - mn);
            float fv = __expf(ft + mv - mn);
            float cn = fv * cv + iv * tanhf(zt);
            float nn = fv * nv + iv;
            hn = (cn / fmaxf(nn, 1e-6f)) / (1.f + __expf(-ot));
            cv = cn; nv = nn; mv = mn;
        }

        unsigned short h16 = __builtin_bit_cast(unsigned short, (f16)hn);
        int other = __shfl_xor((int)h16, 16);
        if ((el2 & 1) == 0) {
            unsigned word = (unsigned)h16 | ((unsigned)(unsigned short)other << 16);
            __hip_atomic_store(hbuf + (size_t)t * (B_ * HW_)
                                    + (size_t)b * HW_ + et * 18 + (el2 >> 1),
                               word, __ATOMIC_RELAXED, __HIP_MEMORY_SCOPE_AGENT);
        }

        __syncthreads();
        if (tid == 0)
            __hip_atomic_fetch_add(barp, 1u, __ATOMIC_RELAXED,
                                   __HIP_MEMORY_SCOPE_AGENT);

        if (t + 1 < S_)
            pf = *(const f16x4*)(pre2 + ((size_t)(t + 1) * B_ + b) * D_ * 4
                                      + ec2 * 4);
    }
}

// ---------------------------------------------------------------------------
// 4) BatchNorm part 1: fold in layer-5 h (x += h, writeback) + partial sums.
// ---------------------------------------------------------------------------
__global__ __launch_bounds__(256) void k_bnpart(float* __restrict__ x,
                                                const f16* __restrict__ h,
                                                float* __restrict__ part) {
    int b = blockIdx.x;
    for (int c = threadIdx.x; c < D_; c += 256) {
        float s1 = 0.f, s2 = 0.f;
        for (int t = 0; t < S_; ++t) {
            size_t xi = (size_t)(b * S_ + t) * D_ + c;
            float v = x[xi] + (float)h[((size_t)t * B_ + b) * KP_ + c];
            x[xi] = v;
            s1 += v;
            s2 += v * v;
        }
        part[(size_t)b * 1152 + c]       = s1;
        part[(size_t)b * 1152 + 576 + c] = s2;
    }
}

__global__ __launch_bounds__(64) void k_bnfinal(const float* __restrict__ part,
                                                const float* __restrict__ bn_g,
                                                const float* __restrict__ bn_b,
                                                float* __restrict__ sc,
                                                float* __restrict__ sh) {
    int d = blockIdx.x * 64 + threadIdx.x;
    if (d >= D_) return;
    float s1 = 0.f, s2 = 0.f;
    for (int w = 0; w < 256; ++w) {
        s1 += part[(size_t)w * 1152 + d];
        s2 += part[(size_t)w * 1152 + 576 + d];
    }
    float mu  = s1 * (1.f / M_);
    float var = fmaxf(s2 * (1.f / M_) - mu * mu, 0.f);
    float s   = bn_g[d] * rsqrtf(var + 1e-5f);
    sc[d] = s;
    sh[d] = bn_b[d] - mu * s;
}

// ---------------------------------------------------------------------------
// 5) final projection + tanh
// ---------------------------------------------------------------------------
__global__ __launch_bounds__(128) void k_final(const float* __restrict__ x,
                                               const float* __restrict__ sc,
                                               const float* __restrict__ sh,
                                               const float* __restrict__ w6,
                                               const float* __restrict__ b6,
                                               float* __restrict__ out) {
    int b = blockIdx.x / 20;
    int p = blockIdx.x - b * 20;
    float a0 = 0.f, a1 = 0.f;
    for (int q = threadIdx.x; q < OUTIN_; q += 128) {
        int u = p * OUTIN_ + q;
        int d = u / 40, s = u - d * 40;
        float v = x[((size_t)b * S_ + s) * D_ + d] * sc[d] + sh[d];
        a0 = fmaf(v, w6[q * 2 + 0], a0);
        a1 = fmaf(v, w6[q * 2 + 1], a1);
    }
    __shared__ float r0[128], r1[128];
    r0[threadIdx.x] = a0;
    r1[threadIdx.x] = a1;
    __syncthreads();
    for (int off = 64; off; off >>= 1) {
        if (threadIdx.x < off) {
            r0[threadIdx.x] += r0[threadIdx.x + off];
            r1[threadIdx.x] += r1[threadIdx.x + off];
        }
        __syncthreads();
    }
    if (threadIdx.x == 0) {
        out[((size_t)b * 20 + p) * 2 + 0] = tanhf(r0[0] + b6[0]);
        out[((size_t)b * 20 + p) * 2 + 1] = tanhf(r1[0] + b6[1]);
    }
}

// ---------------------------------------------------------------------------
extern "C" void kernel_launch(void* const* d_in, const int* in_sizes, int n_in,
                              void* d_out, int out_size, void* d_ws, size_t ws_size,
                              hipStream_t stream) {
    const float* inp  = (const float*)d_in[0];
    const float* Wg   = (const float*)d_in[1];
    const float* Rg   = (const float*)d_in[2];
    const float* bg   = (const float*)d_in[3];
    const float* ln_g = (const float*)d_in[4];
    const float* ln_b = (const float*)d_in[5];
    const float* bn_g = (const float*)d_in[6];
    const float* bn_b = (const float*)d_in[7];
    const float* w6   = (const float*)d_in[8];
    const float* b6   = (const float*)d_in[9];
    float* out = (float*)d_out;

    float* ws = (float*)d_ws;
    size_t off = 0;
    float*    x    = ws + off;            off += (size_t)M_ * D_;
    f16*      pre2 = (f16*)(ws + off);    off += (size_t)M_ * N_ / 2;
    unsigned* hbuf = (unsigned*)(ws + off); off += (size_t)S_ * B_ * HW_ / 1; // u32==f32 slots
    f16*      Wt   = (f16*)(ws + off);    off += (size_t)NB_ * 4 * D_ * KP_ / 2;
    f16*      Rt   = (f16*)(ws + off);    off += (size_t)NB_ * 4 * D_ * KP_ / 2;
    float*    lmu  = ws + off;            off += M_;
    float*    lrs  = ws + off;            off += M_;
    float*    part = ws + off;            off += 256 * 1152;
    float*    sc   = ws + off;            off += 576;
    float*    sh   = ws + off;            off += 576;
    unsigned* bar  = (unsigned*)(ws + off); off += 16 * BSTRIDE_;

    hipMemsetAsync(bar, 0, 16 * BSTRIDE_ * sizeof(unsigned), stream);

    k_prep<<<dim3(18, 18, 48), 256, 0, stream>>>(Wg, Rg, Wt, Rt);
    k_transpose<<<dim3(9, B_), 256, 0, stream>>>(inp, x);

    for (int l = 0; l < NB_; ++l) {
        const f16*   Wtl = Wt + (size_t)l * 4 * D_ * KP_;
        const f16*   Rtl = Rt + (size_t)l * 4 * D_ * KP_;
        const float* bgl = bg + (size_t)l * N_;
        const float* lgl = ln_g + (size_t)l * D_;
        const float* lbl = ln_b + (size_t)l * D_;

        k_addh_lnstats<<<M_ / 4, 256, 0, stream>>>(x, (const f16*)hbuf,
                                                   l > 0 ? 1 : 0, lmu, lrs);
        k_pregemm<<<dim3(80, 18), 256, 0, stream>>>(x, Wtl, bgl, lgl, lbl,
                                                    lmu, lrs, pre2);
        k_rec_persist<<<dim3(16, 16), 576, 0, stream>>>(Rtl, pre2, hbuf, bar, l);
    }

    k_bnpart<<<B_, 256, 0, stream>>>(x, (const f16*)hbuf, part);
    k_bnfinal<<<9, 64, 0, stream>>>(part, bn_g, bn_b, sc, sh);
    k_final<<<B_ * 20, 128, 0, stream>>>(x, sc, sh, w6, b6, out);
}

// Round 9
// 1644.730 us; speedup vs baseline: 1.0701x; 1.0701x over previous
//
#include <hip/hip_runtime.h>
#include <math.h>

#define B_ 256
#define D_ 564
#define S_ 40
#define NB_ 6
#define N_ 2256          // 4*D
#define M_ 10240         // B*S
#define DD_ 318096       // D*D
#define KP_ 576          // D padded to multiple of 32 for MFMA K
#define OUTIN_ 1128
#define HW_ 288          // u32 words per h row (576 f16)
#define BSTRIDE_ 32      // u32 stride between per-bg barrier counters (128 B)

typedef _Float16 f16;
typedef _Float16 f16x4 __attribute__((ext_vector_type(4)));
typedef _Float16 f16x8 __attribute__((ext_vector_type(8)));
typedef float    f32x4 __attribute__((ext_vector_type(4)));

// ---------------------------------------------------------------------------
// P) prep: W,R (l,g,k,e) fp32 -> (l,g,e,k) fp16, k padded 564->576 with zeros
// ---------------------------------------------------------------------------
__global__ __launch_bounds__(256) void k_prep(const float* __restrict__ Wg,
                                              const float* __restrict__ Rg,
                                              f16* __restrict__ Wt,
                                              f16* __restrict__ Rt) {
    __shared__ float tile[32][33];
    int bz  = blockIdx.z;            // 0..47
    int sel = bz / 24;               // 0 = W, 1 = R
    int lg  = bz - sel * 24;         // layer*4 + gate
    const float* src = (sel ? Rg : Wg) + (size_t)lg * DD_;
    f16*         dst = (sel ? Rt : Wt) + (size_t)lg * (D_ * KP_);
    int k0 = blockIdx.x * 32, e0 = blockIdx.y * 32;
    int j = threadIdx.x & 31;
    for (int i = threadIdx.x >> 5; i < 32; i += 8) {
        int k = k0 + i, e = e0 + j;
        tile[i][j] = (k < D_ && e < D_) ? src[(size_t)k * D_ + e] : 0.f;
    }
    __syncthreads();
    for (int i = threadIdx.x >> 5; i < 32; i += 8) {
        int e = e0 + i, k = k0 + j;
        if (e < D_ && k < KP_) dst[(size_t)e * KP_ + k] = (f16)tile[j][i];
    }
}

// ---------------------------------------------------------------------------
// 0) transpose inp (B, D, S) -> x (B, S, D)
// ---------------------------------------------------------------------------
__global__ __launch_bounds__(256) void k_transpose(const float* __restrict__ inp,
                                                   float* __restrict__ x) {
    __shared__ float tile[64][41];
    int b  = blockIdx.y;
    int d0 = blockIdx.x * 64;
    const float* ip = inp + (size_t)b * (D_ * S_);
    for (int idx = threadIdx.x; idx < 64 * 40; idx += 256) {
        int i = idx / 40, s = idx - i * 40;
        if (d0 + i < D_) tile[i][s] = ip[(size_t)(d0 + i) * S_ + s];
    }
    __syncthreads();
    float* xp = x + (size_t)b * (D_ * S_);
    for (int idx = threadIdx.x; idx < 40 * 64; idx += 256) {
        int j = idx & 63, s = idx >> 6;
        if (d0 + j < D_) xp[(size_t)s * D_ + d0 + j] = tile[j][s];
    }
}

// ---------------------------------------------------------------------------
// 1) fused: x += h (prev layer, optional) + LayerNorm row stats
//    h layout (S, B, KP) f16
// ---------------------------------------------------------------------------
__global__ __launch_bounds__(256) void k_addh_lnstats(float* __restrict__ x,
                                                      const f16* __restrict__ h,
                                                      int addh,
                                                      float* __restrict__ lmu,
                                                      float* __restrict__ lrs) {
    int row  = blockIdx.x * 4 + (threadIdx.x >> 6);
    int lane = threadIdx.x & 63;
    float* xp = x + (size_t)row * D_;
    int b = row / S_, s = row - b * S_;
    const f16* hp = h + ((size_t)s * B_ + b) * KP_;
    float s1 = 0.f, s2 = 0.f;
    if (addh) {
        for (int i = lane; i < D_; i += 64) {
            float v = xp[i] + (float)hp[i];
            xp[i] = v;
            s1 += v;
            s2 += v * v;
        }
    } else {
        for (int i = lane; i < D_; i += 64) {
            float v = xp[i];
            s1 += v;
            s2 += v * v;
        }
    }
    for (int off = 32; off; off >>= 1) {
        s1 += __shfl_down(s1, off);
        s2 += __shfl_down(s2, off);
    }
    if (lane == 0) {
        float mu  = s1 * (1.f / D_);
        float var = fmaxf(s2 * (1.f / D_) - mu * mu, 0.f);
        lmu[row] = mu;
        lrs[row] = rsqrtf(var + 1e-5f);
    }
}

// ---------------------------------------------------------------------------
// 1b) apply LN + fp16 convert: hA (10240, 576) fp16, pad zeros
// ---------------------------------------------------------------------------
__global__ __launch_bounds__(256) void k_lnapply(const float* __restrict__ x,
                                                 const float* __restrict__ lg,
                                                 const float* __restrict__ lb,
                                                 const float* __restrict__ lmu,
                                                 const float* __restrict__ lrs,
                                                 f16* __restrict__ hA) {
    int idx = blockIdx.x * 256 + threadIdx.x;   // M_*72 slots
    int row = idx / 72, kq = idx - row * 72;
    int k   = kq * 8;
    float mu = lmu[row], rs = lrs[row];
    const float* xp = x + (size_t)row * D_;
    f16x8 o;
    if (kq < 70) {
        float4 v0 = *(const float4*)(xp + k);
        float4 v1 = *(const float4*)(xp + k + 4);
        float4 g0 = *(const float4*)(lg + k);
        float4 g1 = *(const float4*)(lg + k + 4);
        float4 b0 = *(const float4*)(lb + k);
        float4 b1 = *(const float4*)(lb + k + 4);
        o[0] = (f16)((v0.x - mu) * rs * g0.x + b0.x);
        o[1] = (f16)((v0.y - mu) * rs * g0.y + b0.y);
        o[2] = (f16)((v0.z - mu) * rs * g0.z + b0.z);
        o[3] = (f16)((v0.w - mu) * rs * g0.w + b0.w);
        o[4] = (f16)((v1.x - mu) * rs * g1.x + b1.x);
        o[5] = (f16)((v1.y - mu) * rs * g1.y + b1.y);
        o[6] = (f16)((v1.z - mu) * rs * g1.z + b1.z);
        o[7] = (f16)((v1.w - mu) * rs * g1.w + b1.w);
    } else {
#pragma unroll
        for (int j = 0; j < 8; ++j) {
            int kk = k + j;
            float v = (kk < D_) ? (xp[kk] - mu) * rs * lg[kk] + lb[kk] : 0.f;
            o[j] = (f16)v;
        }
    }
    *(f16x8*)(hA + (size_t)row * KP_ + k) = o;
}

// ---------------------------------------------------------------------------
// 2) pre-GEMM (MFMA fp16), 128x128 tile, 4 waves, 4x4 frags/wave, A from hA.
//    -> pre2 layout (s, b, e, gate) f16
// ---------------------------------------------------------------------------
__global__ __launch_bounds__(256) void k_pregemm(const f16* __restrict__ hA,
                                                 const f16* __restrict__ Wt,  // (4,564,576)
                                                 const float* __restrict__ bgl,
                                                 f16* __restrict__ pre2) {
    __shared__ __align__(16) f16 As[128 * 40];
    __shared__ __align__(16) f16 Bs[128 * 40];
    const int tid  = threadIdx.x;
    const int wave = tid >> 6, lane = tid & 63;
    const int quad = lane >> 4, l16 = lane & 15;
    const int wm = wave & 1, wn = wave >> 1;
    const int m0 = blockIdx.x * 128, n0 = blockIdx.y * 128;

    // A-load role: row am, k-half ah (16 halves each)
    const int am = tid & 127, ah = tid >> 7;
    const f16* ap = hA + (size_t)(m0 + am) * KP_;

    // B-load role: col bn2, k-half bkc
    const int bn2 = tid & 127, bkc = tid >> 7;
    const int nj  = n0 + bn2;
    const bool nok = nj < N_;
    const int njc = nok ? nj : N_ - 1;
    const int gj  = njc / D_, ej = njc - gj * D_;
    const f16* wp = Wt + (size_t)(gj * D_ + ej) * KP_;

    f32x4 acc[4][4];
#pragma unroll
    for (int i = 0; i < 4; ++i)
#pragma unroll
        for (int j = 0; j < 4; ++j) acc[i][j] = (f32x4){0.f, 0.f, 0.f, 0.f};

    for (int k0 = 0; k0 < KP_; k0 += 32) {
        f16x8 a0 = *(const f16x8*)(ap + k0 + ah * 16);
        f16x8 a1 = *(const f16x8*)(ap + k0 + ah * 16 + 8);
        f16x8 b0 = (f16x8){}, b1 = (f16x8){};
        if (nok) {
            b0 = *(const f16x8*)(wp + k0 + bkc * 16);
            b1 = *(const f16x8*)(wp + k0 + bkc * 16 + 8);
        }
        __syncthreads();
        *(f16x8*)(As + am * 40 + ah * 16)       = a0;
        *(f16x8*)(As + am * 40 + ah * 16 + 8)   = a1;
        *(f16x8*)(Bs + bn2 * 40 + bkc * 16)     = b0;
        *(f16x8*)(Bs + bn2 * 40 + bkc * 16 + 8) = b1;
        __syncthreads();
        f16x8 bf[4];
#pragma unroll
        for (int fn = 0; fn < 4; ++fn)
            bf[fn] = *(const f16x8*)(Bs + (wn * 64 + fn * 16 + l16) * 40 + quad * 8);
#pragma unroll
        for (int fm = 0; fm < 4; ++fm) {
            f16x8 af = *(const f16x8*)(As + (wm * 64 + fm * 16 + l16) * 40 + quad * 8);
#pragma unroll
            for (int fn = 0; fn < 4; ++fn)
                acc[fm][fn] = __builtin_amdgcn_mfma_f32_16x16x32_f16(
                                  af, bf[fn], acc[fm][fn], 0, 0, 0);
        }
    }

#pragma unroll
    for (int fn = 0; fn < 4; ++fn) {
        int ncol = n0 + wn * 64 + fn * 16 + l16;
        if (ncol >= N_) continue;
        float bias = bgl[ncol];
        int g2 = ncol / D_, e2 = ncol - g2 * D_;
#pragma unroll
        for (int fm = 0; fm < 4; ++fm)
#pragma unroll
            for (int r = 0; r < 4; ++r) {
                int mm = m0 + wm * 64 + fm * 16 + quad * 4 + r;
                int bb = mm / S_, ss2 = mm - bb * S_;
                pre2[(((size_t)ss2 * B_ + bb) * D_ + e2) * 4 + g2] =
                    (f16)(acc[fm][fn][r] + bias);
            }
    }
}

// ---------------------------------------------------------------------------
// 3) persistent sLSTM recurrence — round-6 protocol verbatim:
//    padded per-bg counters, asm sc0/sc1 poll, fetch_add arrive (RMW arrive
//    is REQUIRED: plain-store arrive raced in round 8).
// ---------------------------------------------------------------------------
__global__ __launch_bounds__(576, 1) void k_rec_persist(
        const f16* __restrict__ Rt,      // (4,564,576) layer slice
        const f16* __restrict__ pre2,    // (40,256,564,4) f16
        unsigned* __restrict__ hbuf,     // (40, 256, 288) u32
        unsigned* __restrict__ bar,      // 16 counters, stride BSTRIDE_ u32
        int layer) {
    __shared__ __align__(16) f16 hs[16 * 584];   // h tile, padded rows
    __shared__ __align__(16) float gbuf[144 * 16];

    const int tid  = threadIdx.x;
    const int et   = blockIdx.x;
    const int bg   = blockIdx.y;
    const int wave = tid >> 6, lane = tid & 63;
    const int quad = lane >> 4, l16 = lane & 15;

    const int c  = wave * 16 + l16;
    const int g  = c / 36, el = c - g * 36;
    const int e  = et * 36 + el;
    const int ec = (e < D_) ? e : D_ - 1;

    f16x8 breg[18];
    {
        const f16* rp = Rt + (size_t)(g * D_ + ec) * KP_ + quad * 8;
#pragma unroll
        for (int kc = 0; kc < 18; ++kc)
            breg[kc] = *(const f16x8*)(rp + kc * 32);
    }

    const int b_loc = tid & 15, el2 = tid >> 4;
    const int e2  = et * 36 + el2;
    const int b   = bg * 16 + b_loc;
    const bool eok = (e2 < D_);
    const int ec2 = eok ? e2 : D_ - 1;

    float cv = 0.f, nv = 0.f, mv = 0.f;

    unsigned* barp = bar + bg * BSTRIDE_;
    const unsigned base = (unsigned)layer * 640u;

    f16x4 pf = *(const f16x4*)(pre2 + (size_t)b * D_ * 4 + ec2 * 4);

    for (int t = 0; t < S_; ++t) {
        if (t > 0) {
            if (tid == 0) {
                unsigned tgt = base + 16u * (unsigned)t;
                for (;;) {
                    unsigned v;
                    asm volatile(
                        "global_load_dword %0, %1, off sc0 sc1\n\t"
                        "s_waitcnt vmcnt(0)"
                        : "=v"(v) : "v"(barp) : "memory");
                    if (v >= tgt) break;
                    __builtin_amdgcn_s_sleep(1);
                }
            }
            __syncthreads();
            const unsigned long long* hsrc = (const unsigned long long*)
                (hbuf + (size_t)(t - 1) * (B_ * HW_) + (size_t)bg * 16 * HW_);
#pragma unroll
            for (int p = 0; p < 4; ++p) {
                int ch  = tid + p * 576;
                int row = ch / 144, col = ch - row * 144;
                unsigned long long v = __hip_atomic_load(
                    hsrc + (size_t)row * 144 + col,
                    __ATOMIC_RELAXED, __HIP_MEMORY_SCOPE_AGENT);
                *(unsigned long long*)(hs + row * 584 + col * 4) = v;
            }
            __syncthreads();
            f32x4 a0 = (f32x4){0.f, 0.f, 0.f, 0.f};
            f32x4 a1 = (f32x4){0.f, 0.f, 0.f, 0.f};
            const f16* hl = hs + l16 * 584 + quad * 8;
#pragma unroll
            for (int kc = 0; kc < 18; kc += 2) {
                f16x8 f0 = *(const f16x8*)(hl + kc * 32);
                f16x8 f1 = *(const f16x8*)(hl + kc * 32 + 32);
                a0 = __builtin_amdgcn_mfma_f32_16x16x32_f16(f0, breg[kc],     a0, 0, 0, 0);
                a1 = __builtin_amdgcn_mfma_f32_16x16x32_f16(f1, breg[kc + 1], a1, 0, 0, 0);
            }
            f32x4 acc = a0 + a1;
#pragma unroll
            for (int r = 0; r < 4; ++r)
                gbuf[c * 16 + quad * 4 + r] = acc[r];
            __syncthreads();
        }

        float hn = 0.f;
        if (eok) {
            float it = (float)pf[0];
            float ft = (float)pf[1];
            float zt = (float)pf[2];
            float ot = (float)pf[3];
            if (t > 0) {
                it += gbuf[(0 * 36 + el2) * 16 + b_loc];
                ft += gbuf[(1 * 36 + el2) * 16 + b_loc];
                zt += gbuf[(2 * 36 + el2) * 16 + b_loc];
                ot += gbuf[(3 * 36 + el2) * 16 + b_loc];
            }
            float mn = fmaxf(ft + mv, it);
            float iv = __expf(it - mn);
            float fv = __expf(ft + mv - mn);
            float cn = fv * cv + iv * tanhf(zt);
            float nn = fv * nv + iv;
            hn = (cn / fmaxf(nn, 1e-6f)) / (1.f + __expf(-ot));
            cv = cn; nv = nn; mv = mn;
        }

        unsigned short h16 = __builtin_bit_cast(unsigned short, (f16)hn);
        int other = __shfl_xor((int)h16, 16);
        if ((el2 & 1) == 0) {
            unsigned word = (unsigned)h16 | ((unsigned)(unsigned short)other << 16);
            __hip_atomic_store(hbuf + (size_t)t * (B_ * HW_)
                                    + (size_t)b * HW_ + et * 18 + (el2 >> 1),
                               word, __ATOMIC_RELAXED, __HIP_MEMORY_SCOPE_AGENT);
        }

        // arrive: syncthreads drains vmcnt in every wave; RMW arrive lands
        // behind the drained h stores at the coherence point.
        __syncthreads();
        if (tid == 0)
            __hip_atomic_fetch_add(barp, 1u, __ATOMIC_RELAXED,
                                   __HIP_MEMORY_SCOPE_AGENT);

        if (t + 1 < S_)
            pf = *(const f16x4*)(pre2 + ((size_t)(t + 1) * B_ + b) * D_ * 4
                                      + ec2 * 4);
    }
}

// ---------------------------------------------------------------------------
// 4) BatchNorm part 1: fold in layer-5 h (x += h, writeback) + partial sums.
// ---------------------------------------------------------------------------
__global__ __launch_bounds__(256) void k_bnpart(float* __restrict__ x,
                                                const f16* __restrict__ h,
                                                float* __restrict__ part) {
    int b = blockIdx.x;
    for (int c = threadIdx.x; c < D_; c += 256) {
        float s1 = 0.f, s2 = 0.f;
        for (int t = 0; t < S_; ++t) {
            size_t xi = (size_t)(b * S_ + t) * D_ + c;
            float v = x[xi] + (float)h[((size_t)t * B_ + b) * KP_ + c];
            x[xi] = v;
            s1 += v;
            s2 += v * v;
        }
        part[(size_t)b * 1152 + c]       = s1;
        part[(size_t)b * 1152 + 576 + c] = s2;
    }
}

__global__ __launch_bounds__(64) void k_bnfinal(const float* __restrict__ part,
                                                const float* __restrict__ bn_g,
                                                const float* __restrict__ bn_b,
                                                float* __restrict__ sc,
                                                float* __restrict__ sh) {
    int d = blockIdx.x * 64 + threadIdx.x;
    if (d >= D_) return;
    float s1 = 0.f, s2 = 0.f;
    for (int w = 0; w < 256; ++w) {
        s1 += part[(size_t)w * 1152 + d];
        s2 += part[(size_t)w * 1152 + 576 + d];
    }
    float mu  = s1 * (1.f / M_);
    float var = fmaxf(s2 * (1.f / M_) - mu * mu, 0.f);
    float s   = bn_g[d] * rsqrtf(var + 1e-5f);
    sc[d] = s;
    sh[d] = bn_b[d] - mu * s;
}

// ---------------------------------------------------------------------------
// 5) final projection + tanh
// ---------------------------------------------------------------------------
__global__ __launch_bounds__(128) void k_final(const float* __restrict__ x,
                                               const float* __restrict__ sc,
                                               const float* __restrict__ sh,
                                               const float* __restrict__ w6,
                                               const float* __restrict__ b6,
                                               float* __restrict__ out) {
    int b = blockIdx.x / 20;
    int p = blockIdx.x - b * 20;
    float a0 = 0.f, a1 = 0.f;
    for (int q = threadIdx.x; q < OUTIN_; q += 128) {
        int u = p * OUTIN_ + q;
        int d = u / 40, s = u - d * 40;
        float v = x[((size_t)b * S_ + s) * D_ + d] * sc[d] + sh[d];
        a0 = fmaf(v, w6[q * 2 + 0], a0);
        a1 = fmaf(v, w6[q * 2 + 1], a1);
    }
    __shared__ float r0[128], r1[128];
    r0[threadIdx.x] = a0;
    r1[threadIdx.x] = a1;
    __syncthreads();
    for (int off = 64; off; off >>= 1) {
        if (threadIdx.x < off) {
            r0[threadIdx.x] += r0[threadIdx.x + off];
            r1[threadIdx.x] += r1[threadIdx.x + off];
        }
        __syncthreads();
    }
    if (threadIdx.x == 0) {
        out[((size_t)b * 20 + p) * 2 + 0] = tanhf(r0[0] + b6[0]);
        out[((size_t)b * 20 + p) * 2 + 1] = tanhf(r1[0] + b6[1]);
    }
}

// ---------------------------------------------------------------------------
extern "C" void kernel_launch(void* const* d_in, const int* in_sizes, int n_in,
                              void* d_out, int out_size, void* d_ws, size_t ws_size,
                              hipStream_t stream) {
    const float* inp  = (const float*)d_in[0];
    const float* Wg   = (const float*)d_in[1];
    const float* Rg   = (const float*)d_in[2];
    const float* bg   = (const float*)d_in[3];
    const float* ln_g = (const float*)d_in[4];
    const float* ln_b = (const float*)d_in[5];
    const float* bn_g = (const float*)d_in[6];
    const float* bn_b = (const float*)d_in[7];
    const float* w6   = (const float*)d_in[8];
    const float* b6   = (const float*)d_in[9];
    float* out = (float*)d_out;

    float* ws = (float*)d_ws;
    size_t off = 0;
    float*    x    = ws + off;            off += (size_t)M_ * D_;
    f16*      pre2 = (f16*)(ws + off);    off += (size_t)M_ * N_ / 2;
    // U region: hA (M_ x KP_ f16) and hbuf (S_ x B_ x 288 u32) — identical
    // 11.80 MB sizes, disjoint lifetimes within each layer:
    // addh_lnstats reads hbuf -> lnapply writes hA -> pregemm reads hA ->
    // rec writes hbuf.
    f16*      hA   = (f16*)(ws + off);
    unsigned* hbuf = (unsigned*)(ws + off); off += (size_t)M_ * KP_ / 2;
    f16*      Wt   = (f16*)(ws + off);    off += (size_t)NB_ * 4 * D_ * KP_ / 2;
    f16*      Rt   = (f16*)(ws + off);    off += (size_t)NB_ * 4 * D_ * KP_ / 2;
    float*    lmu  = ws + off;            off += M_;
    float*    lrs  = ws + off;            off += M_;
    float*    part = ws + off;            off += 256 * 1152;
    float*    sc   = ws + off;            off += 576;
    float*    sh   = ws + off;            off += 576;
    unsigned* bar  = (unsigned*)(ws + off); off += 16 * BSTRIDE_;

    hipMemsetAsync(bar, 0, 16 * BSTRIDE_ * sizeof(unsigned), stream);

    k_prep<<<dim3(18, 18, 48), 256, 0, stream>>>(Wg, Rg, Wt, Rt);
    k_transpose<<<dim3(9, B_), 256, 0, stream>>>(inp, x);

    for (int l = 0; l < NB_; ++l) {
        const f16*   Wtl = Wt + (size_t)l * 4 * D_ * KP_;
        const f16*   Rtl = Rt + (size_t)l * 4 * D_ * KP_;
        const float* bgl = bg + (size_t)l * N_;
        const float* lgl = ln_g + (size_t)l * D_;
        const float* lbl = ln_b + (size_t)l * D_;

        k_addh_lnstats<<<M_ / 4, 256, 0, stream>>>(x, (const f16*)hbuf,
                                                   l > 0 ? 1 : 0, lmu, lrs);
        k_lnapply<<<M_ * 72 / 256, 256, 0, stream>>>(x, lgl, lbl, lmu, lrs, hA);
        k_pregemm<<<dim3(80, 18), 256, 0, stream>>>(hA, Wtl, bgl, pre2);
        k_rec_persist<<<dim3(16, 16), 576, 0, stream>>>(Rtl, pre2, hbuf, bar, l);
    }

    k_bnpart<<<B_, 256, 0, stream>>>(x, (const f16*)hbuf, part);
    k_bnfinal<<<9, 64, 0, stream>>>(part, bn_g, bn_b, sc, sh);
    k_final<<<B_ * 20, 128, 0, stream>>>(x, sc, sh, w6, b6, out);
}